// Round 10
// baseline (108.234 us; speedup 1.0000x reference)
//
#include <hip/hip_runtime.h>
#include <math.h>

#define NQ   12
#define NL   4
#define QBLK 512
// LDS layout (__fp16 units): [0,6144) B1 gate tables (12 x 512);
// floats at +6144: xv[0..48) enc_c[64..112) enc_s[128..176) Gt[192..576);
// state buffers at 8192 + i*8192 (4 x 16KB). Total 81920 B -> 2 blocks/CU.
#define SOFF(i) (8192 + (i) * 8192)

typedef float v4f  __attribute__((ext_vector_type(4)));
typedef __fp16 v8h __attribute__((ext_vector_type(8)));
typedef unsigned v4u __attribute__((ext_vector_type(4)));

// Inverse CNOT-ring map (apply CNOTs in forward order). GF(2)-linear.
__device__ __forceinline__ constexpr int sigma_inv_c(int i) {
    int j = i;
    for (int c = 0; c < NQ; ++c) {
        int t = (c + 1) % NQ;
        int cb = (j >> (NQ - 1 - c)) & 1;
        j ^= cb << (NQ - 1 - t);
    }
    return j;
}

// State line swizzle: keeps fragment reads and column writes <=2-way.
__device__ __forceinline__ constexpr int lswz(int l) {
    return l ^ (((l >> 3) ^ (l >> 7)) & 7);
}

__device__ __forceinline__ unsigned pk2(float a, float b) {
    return __builtin_bit_cast(unsigned, __builtin_amdgcn_cvt_pkrtz(a, b));
}

// Fragment slot: value B[k][n] at hw ((k>>3)*16+n)*8+(k&7).
__device__ __forceinline__ int fslot(int k, int n) {
    return ((k >> 3) * 16 + n) * 8 + (k & 7);
}

// B2 derived in-register from B1 (verified numerically in R2 run, passed).
// B1 word w = (lo: Re(U^T), hi: -Im(U^T)); B2 word = (lo: Im, hi: Re).
// rotate16(w) = (lo: -Im, hi: Re); XOR 0x8000 flips the low f16 sign.
__device__ __forceinline__ v8h derive_b2(v8h b) {
    v4u w = __builtin_bit_cast(v4u, b);
    v4u r;
    #pragma unroll
    for (int i = 0; i < 4; ++i) {
        const unsigned rot = (w[i] >> 16) | (w[i] << 16);
        r[i] = rot ^ 0x8000u;
    }
    return __builtin_bit_cast(v8h, r);
}

// q-split: wave W covers q in {2*qh, 2*qh+1} (qh = W>>2, wv = W&3).
#define READ_FRAGS(AF, SRC)                                                 \
    _Pragma("unroll")                                                       \
    for (int j = 0; j < 2; ++j)                                             \
        AF[j] = __builtin_bit_cast(v8h, *(const uint4*)&sh[(SRC) +          \
                    lswz((((wv) << 6) | ((2 * qh + j) << 4) | nn) * 4 + g) * 8]);

// Gate fragments now live in LDS (B1 only); B2/C2 derived in-register.
#define BLOAD(MAT)                                                          \
    const v8h b1 = *(const v8h*)&sh[(MAT) * 512 + lane * 8];                \
    const v8h b2 = derive_b2(b1);

#define BLOAD2(MATB, MATC)                                                  \
    const v8h b1 = *(const v8h*)&sh[(MATB) * 512 + lane * 8];               \
    const v8h b2 = derive_b2(b1);                                           \
    const v8h c1 = *(const v8h*)&sh[(MATC) * 512 + lane * 8];               \
    const v8h c2 = derive_b2(c1);

#define MFMA_ONE(AF)                                                        \
    _Pragma("unroll")                                                       \
    for (int j = 0; j < 2; ++j) {                                           \
        d1[j] = __builtin_amdgcn_mfma_f32_16x16x32_f16(AF[j], b1, zf, 0, 0, 0); \
        d2[j] = __builtin_amdgcn_mfma_f32_16x16x32_f16(AF[j], b2, zf, 0, 0, 0); \
    }

// In-register B->C chain: phase-B's D output at lane L IS the phase-C
// A-fragment layout: element (2rg, 2rg+1) = pk2(d1[rg], d2[rg]).
#define PACK_AF(AF)                                                         \
    _Pragma("unroll")                                                       \
    for (int j = 0; j < 2; ++j) {                                           \
        v4u t;                                                              \
        _Pragma("unroll")                                                   \
        for (int rg = 0; rg < 4; ++rg) t[rg] = pk2(d1[j][rg], d2[j][rg]);   \
        AF[j] = __builtin_bit_cast(v8h, t);                                 \
    }

#define MFMA_CC(AF)                                                         \
    _Pragma("unroll")                                                       \
    for (int j = 0; j < 2; ++j) {                                           \
        d1[j] = __builtin_amdgcn_mfma_f32_16x16x32_f16(AF[j], c1, zf, 0, 0, 0); \
        d2[j] = __builtin_amdgcn_mfma_f32_16x16x32_f16(AF[j], c2, zf, 0, 0, 0); \
    }

// Keep per-sample compute regions from being cross-pipelined (R2 lesson).
#define SCHB __builtin_amdgcn_sched_barrier(0);

#define WRITE_COLS(DST)                                                     \
    _Pragma("unroll")                                                       \
    for (int j = 0; j < 2; ++j) {                                           \
        const int CCn = (nn << 4) | (wv << 2) | (2 * qh + j);               \
        *(uint4*)&sh[(DST) + lswz(CCn * 4 + g) * 8] =                       \
            make_uint4(pk2(d1[j].x, d2[j].x), pk2(d1[j].y, d2[j].y),        \
                       pk2(d1[j].z, d2[j].z), pk2(d1[j].w, d2[j].w));       \
    }

// Sigma scatter from chained-C output. pre_idx = (nn<<8)|((4g+rg)<<4)|
// (wv<<2)|(qh<<1)|j; slot = ifix2 ^ sigma_inv(rg<<4) ^ (j ? sigma_inv(1) : 0).
#define WRITE_SIGMA2(DST)                                                   \
    _Pragma("unroll")                                                       \
    for (int j = 0; j < 2; ++j) {                                           \
        const int ij = ifix2 ^ (j ? sigma_inv_c(1) : 0);                    \
        _Pragma("unroll")                                                   \
        for (int rg = 0; rg < 4; ++rg) {                                    \
            const int ii = ij ^ sigma_inv_c(rg << 4);                       \
            *(unsigned*)&sh[(DST) + lswz(ii >> 2) * 8 + (ii & 3) * 2] =     \
                pk2(d1[j][rg], d2[j][rg]);                                  \
        }                                                                   \
    }

// Epilogue from chained-C output: 8-pt WHT over (j bit2, rg bits 1:0);
// characters at generators {0x01, 0x20, 0x10}; sign from ifix2.
#define WHT_EPI2(OFF)                                                       \
    { float p8[8];                                                          \
      _Pragma("unroll")                                                     \
      for (int j = 0; j < 2; ++j)                                           \
          _Pragma("unroll")                                                 \
          for (int rg = 0; rg < 4; ++rg)                                    \
              p8[j * 4 + rg] = d1[j][rg] * d1[j][rg] + d2[j][rg] * d2[j][rg]; \
      _Pragma("unroll")                                                     \
      for (int st = 1; st < 8; st <<= 1) {                                  \
          _Pragma("unroll")                                                 \
          for (int i = 0; i < 8; ++i) {                                     \
              if (!(i & st)) {                                              \
                  const float a = p8[i], b = p8[i ^ st];                    \
                  p8[i] = a + b; p8[i ^ st] = a - b;                        \
              }                                                             \
          }                                                                 \
      }                                                                     \
      float vals[NQ];                                                       \
      _Pragma("unroll")                                                     \
      for (int w = 0; w < NQ; ++w) {                                        \
          const int sb = 11 - w;                                            \
          const int fj  = (sigma_inv_c(0x001) >> sb) & 1;                   \
          const int frh = (sigma_inv_c(0x020) >> sb) & 1;                   \
          const int frl = (sigma_inv_c(0x010) >> sb) & 1;                   \
          const float v = p8[fj * 4 + frh * 2 + frl];                       \
          vals[w] = ((ifix2 >> sb) & 1) ? -v : v;                           \
      }                                                                     \
      _Pragma("unroll")                                                     \
      for (int m = 1; m <= 8; m <<= 1) {                                    \
          _Pragma("unroll")                                                 \
          for (int w = 0; w < NQ; ++w) vals[w] += __shfl_xor(vals[w], m);   \
      }                                                                     \
      if ((lane & 15) == 0) {                                               \
          _Pragma("unroll")                                                 \
          for (int w = 0; w < NQ; ++w)                                      \
              red[(OFF) + W * 48 + (lane >> 4) * 12 + w] = vals[w];         \
      } }

__global__ __launch_bounds__(QBLK) void qsim_kernel(
    const float* __restrict__ x,      // (B, 12)
    const float* __restrict__ qw,     // (144,) variational angles
    const float* __restrict__ dw,     // (12, 12)
    const float* __restrict__ db,     // (12,)
    float* __restrict__ out,          // (B, 12)
    int batch)
{
    // Single fused kernel: each block builds the 12 B1 gate-fragment tables
    // in its own LDS (~1-2us, parallel across CUs), then runs the R8 main
    // loop. Removes gate_kernel launch + inter-kernel gap (~46-52us/iter of
    // non-qsim time measured stable across R0-R8).
    __shared__ __align__(16) __fp16 sh[40960];   // 80 KB -> 2 blocks/CU
    float* fb    = (float*)(sh + 6144);
    float* xv    = fb;                // [0..47]
    float* enc_c = fb + 64;           // [64..111]
    float* enc_s = fb + 128;          // [128..175]
    float* Gt    = fb + 192;          // [192..575]: 48 fused 2x2 gates x 8
    float* red   = (float*)(sh + SOFF(0));   // aliases dead state at epilogue

    const int tid  = threadIdx.x;
    const int lane = tid & 63;
    const int W    = tid >> 6;        // wave 0..7
    const int wv   = W & 3;           // CC wave field
    const int qh   = W >> 2;          // q-half selector
    const int base = 4 * blockIdx.x;
    int ss[4];
    #pragma unroll
    for (int i = 0; i < 4; ++i) {
        int s = base + i;
        ss[i] = (s < batch) ? s : batch - 1;   // tail clamp (dup writes benign)
    }
    const int nn = lane & 15, g = lane >> 4;
    const v4f zf = {0.f, 0.f, 0.f, 0.f};

    if (tid < 4 * NQ) {
        const int smp = tid / NQ, j = tid - smp * NQ;
        xv[tid] = x[ss[smp] * NQ + j];
    }
    __syncthreads();
    // Threads 0..47: per-sample encode angles. Threads 64..111: fused
    // RZ*RY*RX 2x2 gates for all (layer, wire). Disjoint LDS regions.
    if (tid < 4 * NQ) {
        const int b0 = (tid / NQ) * NQ;
        float sum = 0.f;
        #pragma unroll
        for (int j = 0; j < NQ; ++j) sum += xv[b0 + j] * xv[b0 + j];
        float inv = rsqrtf(fmaxf(sum, 1e-12f));
        float mx = 0.f;
        #pragma unroll
        for (int j = 0; j < NQ; ++j) mx = fmaxf(mx, fabsf(xv[b0 + j] * inv));
        float ang = 3.14159265358979323846f * (xv[tid] * inv) / (mx + 1e-8f);
        float cc, sn;
        sincosf(0.5f * ang, &sn, &cc);
        enc_c[tid] = cc; enc_s[tid] = sn;
    } else if (tid >= 64 && tid < 64 + NL * NQ) {
        const int t = tid - 64;                   // (layer, wire)
        const int p = (t / NQ) * 3 * NQ + 3 * (t % NQ);
        float t1 = qw[p], t2 = qw[p + 1], t3 = qw[p + 2];
        float a, b, c, d, gr, h;
        sincosf(0.5f * t1, &b, &a);   // RX
        sincosf(0.5f * t2, &d, &c);   // RY
        sincosf(0.5f * t3, &h, &gr);  // RZ
        float m00r =  c * a, m00i =  d * b;
        float m01r = -d * a, m01i = -c * b;
        float m10r =  d * a, m10i = -c * b;
        float m11r =  c * a, m11i = -d * b;
        float* gg = Gt + t * 8;
        gg[0] = gr * m00r + h * m00i;  gg[1] = gr * m00i - h * m00r;
        gg[2] = gr * m01r + h * m01i;  gg[3] = gr * m01i - h * m01r;
        gg[4] = gr * m10r - h * m10i;  gg[5] = gr * m10i + h * m10r;
        gg[6] = gr * m11r - h * m11i;  gg[7] = gr * m11i + h * m11r;
    }
    __syncthreads();

    // ---- build B1 fragment tables: 12 mats x 256 (r,n) entries, 6/thread ----
    #pragma unroll
    for (int e = 0; e < 6; ++e) {
        const int idx = tid * 6 + e;              // 0..3071
        const int mat = idx >> 8, rn = idx & 255;
        const int r = rn >> 4, n = rn & 15;
        const int layer = mat / 3, ph = mat - 3 * layer;
        const int wbase = (ph == 0) ? 8 : (ph == 1) ? 4 : 0;
        float cr = 1.f, ci = 0.f;
        #pragma unroll
        for (int b = 0; b < 4; ++b) {             // bit (3-b) <-> wire wbase+b
            const float* gg = Gt + (layer * NQ + wbase + b) * 8;
            const int rb = (r >> (3 - b)) & 1, nb = (n >> (3 - b)) & 1;
            const float er = gg[(nb * 2 + rb) * 2], ei = gg[(nb * 2 + rb) * 2 + 1];
            const float xr = cr * er - ci * ei, xi = cr * ei + ci * er;
            cr = xr; ci = xi;
        }
        sh[mat * 512 + fslot(2 * r, n)]     = (__fp16)cr;
        sh[mat * 512 + fslot(2 * r + 1, n)] = (__fp16)(-ci);
    }

    // ---- product-state init as phase-A A-fragments (interleaved re/im) ----
    v8h af0[2], af1[2], af2[2], af3[2];
    #define PICK(SMP, WW, B) ((B) ? enc_s[(SMP) * NQ + (WW)] : enc_c[(SMP) * NQ + (WW)])
    #define INIT_AF(AF, SMP)                                                \
    {   float R4[4];                                                        \
        _Pragma("unroll")                                                   \
        for (int t = 0; t < 4; ++t) {                                       \
            const int r = 4 * g + t;                                        \
            R4[t] = PICK(SMP, 8, (r >> 3) & 1) * PICK(SMP, 9, (r >> 2) & 1) \
                  * PICK(SMP, 10, (r >> 1) & 1) * PICK(SMP, 11, r & 1);     \
        }                                                                   \
        const float Pfix = PICK(SMP, 0, (wv >> 1) & 1) * PICK(SMP, 1, wv & 1) \
                         * PICK(SMP, 4, (nn >> 3) & 1) * PICK(SMP, 5, (nn >> 2) & 1) \
                         * PICK(SMP, 6, (nn >> 1) & 1) * PICK(SMP, 7, nn & 1); \
        _Pragma("unroll")                                                   \
        for (int j = 0; j < 2; ++j) {                                       \
            const float Pq = Pfix * PICK(SMP, 2, qh) * PICK(SMP, 3, j);     \
            _Pragma("unroll")                                               \
            for (int t = 0; t < 4; ++t) {                                   \
                AF[j][2 * t]     = (__fp16)(Pq * R4[t]);                    \
                AF[j][2 * t + 1] = (__fp16)0.f;                             \
            }                                                               \
        }                                                                   \
    }
    INIT_AF(af0, 0)
    INIT_AF(af1, 1)
    INIT_AF(af2, 2)
    INIT_AF(af3, 3)
    #undef PICK
    __syncthreads();   // gate tables complete + enc reads done

    // Loop-invariant sigma constant for the chained-C output index map.
    const int ifix2 = sigma_inv_c((nn << 8) | (g << 6) | (wv << 2) | (qh << 1));

    v4f d1[2], d2[2];
    #define READ4                                                           \
        READ_FRAGS(af0, SOFF(0)) READ_FRAGS(af1, SOFF(1))                   \
        READ_FRAGS(af2, SOFF(2)) READ_FRAGS(af3, SOFF(3))
    #define COLS4(MAT)                                                      \
        { BLOAD(MAT)                                                        \
          MFMA_ONE(af0) WRITE_COLS(SOFF(0)) SCHB                            \
          MFMA_ONE(af1) WRITE_COLS(SOFF(1)) SCHB                            \
          MFMA_ONE(af2) WRITE_COLS(SOFF(2)) SCHB                            \
          MFMA_ONE(af3) WRITE_COLS(SOFF(3)) }
    #define CHAIN_S(AF, DST)                                                \
        MFMA_ONE(AF) PACK_AF(AF) MFMA_CC(AF) WRITE_SIGMA2(DST)
    #define CHAIN_E(AF, EOFF)                                               \
        MFMA_ONE(AF) PACK_AF(AF) MFMA_CC(AF) WHT_EPI2(EOFF)

    #pragma unroll 1
    for (int l = 0; l < NL; ++l) {
        if (l > 0) {
            READ4
            __syncthreads();              // all reads landed before writes
        }
        COLS4(l * 3 + 0)                  // phase A: wires 8..11
        __syncthreads();

        READ4
        __syncthreads();                  // reads drained (states dead if last)
        if (l < NL - 1) {
            { BLOAD2(l * 3 + 1, l * 3 + 2)
              CHAIN_S(af0, SOFF(0)) SCHB
              CHAIN_S(af1, SOFF(1)) SCHB
              CHAIN_S(af2, SOFF(2)) SCHB
              CHAIN_S(af3, SOFF(3)) }
            __syncthreads();
        } else {
            { BLOAD2(l * 3 + 1, l * 3 + 2)
              CHAIN_E(af0, 0)    SCHB
              CHAIN_E(af1, 384)  SCHB
              CHAIN_E(af2, 768)  SCHB
              CHAIN_E(af3, 1152) }
        }
    }

    __syncthreads();   // all red partials written (red aliases dead state)
    if (tid < 4 * NQ) {
        const int smp = tid / NQ, w = tid - smp * NQ;
        float acc = 0.f;
        #pragma unroll
        for (int k = 0; k < 32; ++k) acc += red[smp * 384 + k * 12 + w];
        red[1536 + tid] = acc;
    }
    __syncthreads();
    if (tid < 4 * NQ) {
        const int smp = tid / NQ, o = tid - smp * NQ;
        const float* rv = red + 1536 + smp * NQ;
        float v = db[o];
        #pragma unroll
        for (int w = 0; w < NQ; ++w) v += rv[w] * dw[w * NQ + o];
        out[ss[smp] * NQ + o] = tanhf(v);
    }
}

extern "C" void kernel_launch(void* const* d_in, const int* in_sizes, int n_in,
                              void* d_out, int out_size, void* d_ws, size_t ws_size,
                              hipStream_t stream) {
    const float* x  = (const float*)d_in[0];
    const float* qw = (const float*)d_in[1];
    const float* dw = (const float*)d_in[2];
    const float* db = (const float*)d_in[3];
    float* out = (float*)d_out;
    int batch = in_sizes[0] / NQ;
    int nblk = (batch + 3) / 4;
    qsim_kernel<<<nblk, QBLK, 0, stream>>>(x, qw, dw, db, out, batch);
}

// Round 11
// 107.685 us; speedup vs baseline: 1.0051x; 1.0051x over previous
//
#include <hip/hip_runtime.h>
#include <math.h>

#define NQ   12
#define NL   4
#define QBLK 512
// LDS layout (__fp16 units): [0,6144) B1 gate tables (12 x 512);
// floats at +6144: xv[0..48) enc_c[64..112) enc_s[128..176) Gt[192..576);
// state buffers at 8192 + i*8192 (4 x 16KB). Total 81920 B -> 2 blocks/CU.
#define SOFF(i) (8192 + (i) * 8192)

typedef float v4f  __attribute__((ext_vector_type(4)));
typedef __fp16 v8h __attribute__((ext_vector_type(8)));
typedef unsigned v4u __attribute__((ext_vector_type(4)));

// Inverse CNOT-ring map (apply CNOTs in forward order). GF(2)-linear.
__device__ __forceinline__ constexpr int sigma_inv_c(int i) {
    int j = i;
    for (int c = 0; c < NQ; ++c) {
        int t = (c + 1) % NQ;
        int cb = (j >> (NQ - 1 - c)) & 1;
        j ^= cb << (NQ - 1 - t);
    }
    return j;
}

// State line swizzle: keeps fragment reads and column writes <=2-way.
__device__ __forceinline__ constexpr int lswz(int l) {
    return l ^ (((l >> 3) ^ (l >> 7)) & 7);
}

__device__ __forceinline__ unsigned pk2(float a, float b) {
    return __builtin_bit_cast(unsigned, __builtin_amdgcn_cvt_pkrtz(a, b));
}

// Fragment slot: value B[k][n] at hw ((k>>3)*16+n)*8+(k&7).
__device__ __forceinline__ int fslot(int k, int n) {
    return ((k >> 3) * 16 + n) * 8 + (k & 7);
}

// B2 derived in-register from B1 (verified numerically in R2 run, passed).
// B1 word w = (lo: Re(U^T), hi: -Im(U^T)); B2 word = (lo: Im, hi: Re).
// rotate16(w) = (lo: -Im, hi: Re); XOR 0x8000 flips the low f16 sign.
__device__ __forceinline__ v8h derive_b2(v8h b) {
    v4u w = __builtin_bit_cast(v4u, b);
    v4u r;
    #pragma unroll
    for (int i = 0; i < 4; ++i) {
        const unsigned rot = (w[i] >> 16) | (w[i] << 16);
        r[i] = rot ^ 0x8000u;
    }
    return __builtin_bit_cast(v8h, r);
}

// q-split: wave W covers q in {2*qh, 2*qh+1} (qh = W>>2, wv = W&3).
#define READ_FRAGS(AF, SRC)                                                 \
    _Pragma("unroll")                                                       \
    for (int j = 0; j < 2; ++j)                                             \
        AF[j] = __builtin_bit_cast(v8h, *(const uint4*)&sh[(SRC) +          \
                    lswz((((wv) << 6) | ((2 * qh + j) << 4) | nn) * 4 + g) * 8]);

// Gate fragments live in LDS (B1 only); B2/C2 derived in-register.
#define BLOAD(MAT)                                                          \
    const v8h b1 = *(const v8h*)&sh[(MAT) * 512 + lane * 8];                \
    const v8h b2 = derive_b2(b1);

#define BLOAD2(MATB, MATC)                                                  \
    const v8h b1 = *(const v8h*)&sh[(MATB) * 512 + lane * 8];               \
    const v8h b2 = derive_b2(b1);                                           \
    const v8h c1 = *(const v8h*)&sh[(MATC) * 512 + lane * 8];               \
    const v8h c2 = derive_b2(c1);

#define MFMA_ONE(AF)                                                        \
    _Pragma("unroll")                                                       \
    for (int j = 0; j < 2; ++j) {                                           \
        d1[j] = __builtin_amdgcn_mfma_f32_16x16x32_f16(AF[j], b1, zf, 0, 0, 0); \
        d2[j] = __builtin_amdgcn_mfma_f32_16x16x32_f16(AF[j], b2, zf, 0, 0, 0); \
    }

// In-register B->C chain: phase-B's D output at lane L IS the phase-C
// A-fragment layout: element (2rg, 2rg+1) = pk2(d1[rg], d2[rg]).
#define PACK_AF(AF)                                                         \
    _Pragma("unroll")                                                       \
    for (int j = 0; j < 2; ++j) {                                           \
        v4u t;                                                              \
        _Pragma("unroll")                                                   \
        for (int rg = 0; rg < 4; ++rg) t[rg] = pk2(d1[j][rg], d2[j][rg]);   \
        AF[j] = __builtin_bit_cast(v8h, t);                                 \
    }

#define MFMA_CC(AF)                                                         \
    _Pragma("unroll")                                                       \
    for (int j = 0; j < 2; ++j) {                                           \
        d1[j] = __builtin_amdgcn_mfma_f32_16x16x32_f16(AF[j], c1, zf, 0, 0, 0); \
        d2[j] = __builtin_amdgcn_mfma_f32_16x16x32_f16(AF[j], c2, zf, 0, 0, 0); \
    }

// R11: SCHB removed from the main loop (COLS4 / CHAIN_S). LDS caps
// residency at 2 blocks/CU = 4 waves/SIMD, which tolerates up to 128
// VGPR — cross-sample software pipelining is free occupancy-wise.
// SCHB kept ONLY in the epilogue (vals[12]+p8[8] per sample would blow
// registers if overlapped — R4 lesson).
#define SCHB __builtin_amdgcn_sched_barrier(0);

// Per-sample MFMA+pack+write with a distinct accumulator set (D1x,D2x) so
// the compiler can interleave the 4 samples' chains across MFMA latency.
#define COLS_ONE(AF, D1x, D2x, DST)                                         \
    _Pragma("unroll")                                                       \
    for (int j = 0; j < 2; ++j) {                                           \
        D1x[j] = __builtin_amdgcn_mfma_f32_16x16x32_f16(AF[j], b1, zf, 0, 0, 0); \
        D2x[j] = __builtin_amdgcn_mfma_f32_16x16x32_f16(AF[j], b2, zf, 0, 0, 0); \
    }                                                                       \
    _Pragma("unroll")                                                       \
    for (int j = 0; j < 2; ++j) {                                           \
        const int CCn = (nn << 4) | (wv << 2) | (2 * qh + j);               \
        *(uint4*)&sh[(DST) + lswz(CCn * 4 + g) * 8] =                       \
            make_uint4(pk2(D1x[j].x, D2x[j].x), pk2(D1x[j].y, D2x[j].y),    \
                       pk2(D1x[j].z, D2x[j].z), pk2(D1x[j].w, D2x[j].w));   \
    }

#define CHAIN_ONE(AF, D1x, D2x, DST)                                        \
    _Pragma("unroll")                                                       \
    for (int j = 0; j < 2; ++j) {                                           \
        D1x[j] = __builtin_amdgcn_mfma_f32_16x16x32_f16(AF[j], b1, zf, 0, 0, 0); \
        D2x[j] = __builtin_amdgcn_mfma_f32_16x16x32_f16(AF[j], b2, zf, 0, 0, 0); \
    }                                                                       \
    _Pragma("unroll")                                                       \
    for (int j = 0; j < 2; ++j) {                                           \
        v4u t;                                                              \
        _Pragma("unroll")                                                   \
        for (int rg = 0; rg < 4; ++rg) t[rg] = pk2(D1x[j][rg], D2x[j][rg]); \
        AF[j] = __builtin_bit_cast(v8h, t);                                 \
    }                                                                       \
    _Pragma("unroll")                                                       \
    for (int j = 0; j < 2; ++j) {                                           \
        D1x[j] = __builtin_amdgcn_mfma_f32_16x16x32_f16(AF[j], c1, zf, 0, 0, 0); \
        D2x[j] = __builtin_amdgcn_mfma_f32_16x16x32_f16(AF[j], c2, zf, 0, 0, 0); \
    }                                                                       \
    _Pragma("unroll")                                                       \
    for (int j = 0; j < 2; ++j) {                                           \
        const int ij = ifix2 ^ (j ? sigma_inv_c(1) : 0);                    \
        _Pragma("unroll")                                                   \
        for (int rg = 0; rg < 4; ++rg) {                                    \
            const int ii = ij ^ sigma_inv_c(rg << 4);                       \
            *(unsigned*)&sh[(DST) + lswz(ii >> 2) * 8 + (ii & 3) * 2] =     \
                pk2(D1x[j][rg], D2x[j][rg]);                                \
        }                                                                   \
    }

// Epilogue from chained-C output: 8-pt WHT over (j bit2, rg bits 1:0);
// characters at generators {0x01, 0x20, 0x10}; sign from ifix2.
#define WHT_EPI2(OFF)                                                       \
    { float p8[8];                                                          \
      _Pragma("unroll")                                                     \
      for (int j = 0; j < 2; ++j)                                           \
          _Pragma("unroll")                                                 \
          for (int rg = 0; rg < 4; ++rg)                                    \
              p8[j * 4 + rg] = d1[j][rg] * d1[j][rg] + d2[j][rg] * d2[j][rg]; \
      _Pragma("unroll")                                                     \
      for (int st = 1; st < 8; st <<= 1) {                                  \
          _Pragma("unroll")                                                 \
          for (int i = 0; i < 8; ++i) {                                     \
              if (!(i & st)) {                                              \
                  const float a = p8[i], b = p8[i ^ st];                    \
                  p8[i] = a + b; p8[i ^ st] = a - b;                        \
              }                                                             \
          }                                                                 \
      }                                                                     \
      float vals[NQ];                                                       \
      _Pragma("unroll")                                                     \
      for (int w = 0; w < NQ; ++w) {                                        \
          const int sb = 11 - w;                                            \
          const int fj  = (sigma_inv_c(0x001) >> sb) & 1;                   \
          const int frh = (sigma_inv_c(0x020) >> sb) & 1;                   \
          const int frl = (sigma_inv_c(0x010) >> sb) & 1;                   \
          const float v = p8[fj * 4 + frh * 2 + frl];                       \
          vals[w] = ((ifix2 >> sb) & 1) ? -v : v;                           \
      }                                                                     \
      _Pragma("unroll")                                                     \
      for (int m = 1; m <= 8; m <<= 1) {                                    \
          _Pragma("unroll")                                                 \
          for (int w = 0; w < NQ; ++w) vals[w] += __shfl_xor(vals[w], m);   \
      }                                                                     \
      if ((lane & 15) == 0) {                                               \
          _Pragma("unroll")                                                 \
          for (int w = 0; w < NQ; ++w)                                      \
              red[(OFF) + W * 48 + (lane >> 4) * 12 + w] = vals[w];         \
      } }

__global__ __launch_bounds__(QBLK) void qsim_kernel(
    const float* __restrict__ x,      // (B, 12)
    const float* __restrict__ qw,     // (144,) variational angles
    const float* __restrict__ dw,     // (12, 12)
    const float* __restrict__ db,     // (12,)
    float* __restrict__ out,          // (B, 12)
    int batch)
{
    // Single fused kernel (R10) + cross-sample ILP (R11): SCHB removed
    // from the main loop so the 4 samples' MFMA/pack/write chains overlap.
    __shared__ __align__(16) __fp16 sh[40960];   // 80 KB -> 2 blocks/CU
    float* fb    = (float*)(sh + 6144);
    float* xv    = fb;                // [0..47]
    float* enc_c = fb + 64;           // [64..111]
    float* enc_s = fb + 128;          // [128..175]
    float* Gt    = fb + 192;          // [192..575]: 48 fused 2x2 gates x 8
    float* red   = (float*)(sh + SOFF(0));   // aliases dead state at epilogue

    const int tid  = threadIdx.x;
    const int lane = tid & 63;
    const int W    = tid >> 6;        // wave 0..7
    const int wv   = W & 3;           // CC wave field
    const int qh   = W >> 2;          // q-half selector
    const int base = 4 * blockIdx.x;
    int ss[4];
    #pragma unroll
    for (int i = 0; i < 4; ++i) {
        int s = base + i;
        ss[i] = (s < batch) ? s : batch - 1;   // tail clamp (dup writes benign)
    }
    const int nn = lane & 15, g = lane >> 4;
    const v4f zf = {0.f, 0.f, 0.f, 0.f};

    if (tid < 4 * NQ) {
        const int smp = tid / NQ, j = tid - smp * NQ;
        xv[tid] = x[ss[smp] * NQ + j];
    }
    __syncthreads();
    // Threads 0..47: per-sample encode angles. Threads 64..111: fused
    // RZ*RY*RX 2x2 gates for all (layer, wire). Disjoint LDS regions.
    if (tid < 4 * NQ) {
        const int b0 = (tid / NQ) * NQ;
        float sum = 0.f;
        #pragma unroll
        for (int j = 0; j < NQ; ++j) sum += xv[b0 + j] * xv[b0 + j];
        float inv = rsqrtf(fmaxf(sum, 1e-12f));
        float mx = 0.f;
        #pragma unroll
        for (int j = 0; j < NQ; ++j) mx = fmaxf(mx, fabsf(xv[b0 + j] * inv));
        float ang = 3.14159265358979323846f * (xv[tid] * inv) / (mx + 1e-8f);
        float cc, sn;
        sincosf(0.5f * ang, &sn, &cc);
        enc_c[tid] = cc; enc_s[tid] = sn;
    } else if (tid >= 64 && tid < 64 + NL * NQ) {
        const int t = tid - 64;                   // (layer, wire)
        const int p = (t / NQ) * 3 * NQ + 3 * (t % NQ);
        float t1 = qw[p], t2 = qw[p + 1], t3 = qw[p + 2];
        float a, b, c, d, gr, h;
        sincosf(0.5f * t1, &b, &a);   // RX
        sincosf(0.5f * t2, &d, &c);   // RY
        sincosf(0.5f * t3, &h, &gr);  // RZ
        float m00r =  c * a, m00i =  d * b;
        float m01r = -d * a, m01i = -c * b;
        float m10r =  d * a, m10i = -c * b;
        float m11r =  c * a, m11i = -d * b;
        float* gg = Gt + t * 8;
        gg[0] = gr * m00r + h * m00i;  gg[1] = gr * m00i - h * m00r;
        gg[2] = gr * m01r + h * m01i;  gg[3] = gr * m01i - h * m01r;
        gg[4] = gr * m10r - h * m10i;  gg[5] = gr * m10i + h * m10r;
        gg[6] = gr * m11r - h * m11i;  gg[7] = gr * m11i + h * m11r;
    }
    __syncthreads();

    // ---- build B1 fragment tables: 12 mats x 256 (r,n) entries, 6/thread ----
    #pragma unroll
    for (int e = 0; e < 6; ++e) {
        const int idx = tid * 6 + e;              // 0..3071
        const int mat = idx >> 8, rn = idx & 255;
        const int r = rn >> 4, n = rn & 15;
        const int layer = mat / 3, ph = mat - 3 * layer;
        const int wbase = (ph == 0) ? 8 : (ph == 1) ? 4 : 0;
        float cr = 1.f, ci = 0.f;
        #pragma unroll
        for (int b = 0; b < 4; ++b) {             // bit (3-b) <-> wire wbase+b
            const float* gg = Gt + (layer * NQ + wbase + b) * 8;
            const int rb = (r >> (3 - b)) & 1, nb = (n >> (3 - b)) & 1;
            const float er = gg[(nb * 2 + rb) * 2], ei = gg[(nb * 2 + rb) * 2 + 1];
            const float xr = cr * er - ci * ei, xi = cr * ei + ci * er;
            cr = xr; ci = xi;
        }
        sh[mat * 512 + fslot(2 * r, n)]     = (__fp16)cr;
        sh[mat * 512 + fslot(2 * r + 1, n)] = (__fp16)(-ci);
    }

    // ---- product-state init as phase-A A-fragments (interleaved re/im) ----
    v8h af0[2], af1[2], af2[2], af3[2];
    #define PICK(SMP, WW, B) ((B) ? enc_s[(SMP) * NQ + (WW)] : enc_c[(SMP) * NQ + (WW)])
    #define INIT_AF(AF, SMP)                                                \
    {   float R4[4];                                                        \
        _Pragma("unroll")                                                   \
        for (int t = 0; t < 4; ++t) {                                       \
            const int r = 4 * g + t;                                        \
            R4[t] = PICK(SMP, 8, (r >> 3) & 1) * PICK(SMP, 9, (r >> 2) & 1) \
                  * PICK(SMP, 10, (r >> 1) & 1) * PICK(SMP, 11, r & 1);     \
        }                                                                   \
        const float Pfix = PICK(SMP, 0, (wv >> 1) & 1) * PICK(SMP, 1, wv & 1) \
                         * PICK(SMP, 4, (nn >> 3) & 1) * PICK(SMP, 5, (nn >> 2) & 1) \
                         * PICK(SMP, 6, (nn >> 1) & 1) * PICK(SMP, 7, nn & 1); \
        _Pragma("unroll")                                                   \
        for (int j = 0; j < 2; ++j) {                                       \
            const float Pq = Pfix * PICK(SMP, 2, qh) * PICK(SMP, 3, j);     \
            _Pragma("unroll")                                               \
            for (int t = 0; t < 4; ++t) {                                   \
                AF[j][2 * t]     = (__fp16)(Pq * R4[t]);                    \
                AF[j][2 * t + 1] = (__fp16)0.f;                             \
            }                                                               \
        }                                                                   \
    }
    INIT_AF(af0, 0)
    INIT_AF(af1, 1)
    INIT_AF(af2, 2)
    INIT_AF(af3, 3)
    #undef PICK
    __syncthreads();   // gate tables complete + enc reads done

    // Loop-invariant sigma constant for the chained-C output index map.
    const int ifix2 = sigma_inv_c((nn << 8) | (g << 6) | (wv << 2) | (qh << 1));

    // Distinct accumulator sets per sample: lets the scheduler overlap
    // the 4 chains (R11). d1/d2 reused only for the epilogue path.
    v4f d1[2], d2[2], e1[2], e2[2], f1[2], f2[2], h1[2], h2[2];
    #define READ4                                                           \
        READ_FRAGS(af0, SOFF(0)) READ_FRAGS(af1, SOFF(1))                   \
        READ_FRAGS(af2, SOFF(2)) READ_FRAGS(af3, SOFF(3))
    #define COLS4(MAT)                                                      \
        { BLOAD(MAT)                                                        \
          COLS_ONE(af0, d1, d2, SOFF(0))                                    \
          COLS_ONE(af1, e1, e2, SOFF(1))                                    \
          COLS_ONE(af2, f1, f2, SOFF(2))                                    \
          COLS_ONE(af3, h1, h2, SOFF(3)) }
    #define CHAIN4(MATB, MATC)                                              \
        { BLOAD2(MATB, MATC)                                                \
          CHAIN_ONE(af0, d1, d2, SOFF(0))                                   \
          CHAIN_ONE(af1, e1, e2, SOFF(1))                                   \
          CHAIN_ONE(af2, f1, f2, SOFF(2))                                   \
          CHAIN_ONE(af3, h1, h2, SOFF(3)) }
    #define CHAIN_E(AF)                                                     \
        MFMA_ONE(AF)                                                        \
        _Pragma("unroll")                                                   \
        for (int j = 0; j < 2; ++j) {                                       \
            v4u t;                                                          \
            _Pragma("unroll")                                               \
            for (int rg = 0; rg < 4; ++rg) t[rg] = pk2(d1[j][rg], d2[j][rg]); \
            AF[j] = __builtin_bit_cast(v8h, t);                             \
        }                                                                   \
        _Pragma("unroll")                                                   \
        for (int j = 0; j < 2; ++j) {                                       \
            d1[j] = __builtin_amdgcn_mfma_f32_16x16x32_f16(AF[j], c1, zf, 0, 0, 0); \
            d2[j] = __builtin_amdgcn_mfma_f32_16x16x32_f16(AF[j], c2, zf, 0, 0, 0); \
        }

    #pragma unroll 1
    for (int l = 0; l < NL; ++l) {
        if (l > 0) {
            READ4
            __syncthreads();              // all reads landed before writes
        }
        COLS4(l * 3 + 0)                  // phase A: wires 8..11
        __syncthreads();

        READ4
        __syncthreads();                  // reads drained (states dead if last)
        if (l < NL - 1) {
            CHAIN4(l * 3 + 1, l * 3 + 2)  // chained B->C + sigma scatter
            __syncthreads();
        } else {
            { BLOAD2(l * 3 + 1, l * 3 + 2)
              CHAIN_E(af0) WHT_EPI2(0)    SCHB
              CHAIN_E(af1) WHT_EPI2(384)  SCHB
              CHAIN_E(af2) WHT_EPI2(768)  SCHB
              CHAIN_E(af3) WHT_EPI2(1152) }
        }
    }

    __syncthreads();   // all red partials written (red aliases dead state)
    if (tid < 4 * NQ) {
        const int smp = tid / NQ, w = tid - smp * NQ;
        float acc = 0.f;
        #pragma unroll
        for (int k = 0; k < 32; ++k) acc += red[smp * 384 + k * 12 + w];
        red[1536 + tid] = acc;
    }
    __syncthreads();
    if (tid < 4 * NQ) {
        const int smp = tid / NQ, o = tid - smp * NQ;
        const float* rv = red + 1536 + smp * NQ;
        float v = db[o];
        #pragma unroll
        for (int w = 0; w < NQ; ++w) v += rv[w] * dw[w * NQ + o];
        out[ss[smp] * NQ + o] = tanhf(v);
    }
}

extern "C" void kernel_launch(void* const* d_in, const int* in_sizes, int n_in,
                              void* d_out, int out_size, void* d_ws, size_t ws_size,
                              hipStream_t stream) {
    const float* x  = (const float*)d_in[0];
    const float* qw = (const float*)d_in[1];
    const float* dw = (const float*)d_in[2];
    const float* db = (const float*)d_in[3];
    float* out = (float*)d_out;
    int batch = in_sizes[0] / NQ;
    int nblk = (batch + 3) / 4;
    qsim_kernel<<<nblk, QBLK, 0, stream>>>(x, qw, dw, db, out, batch);
}